// Round 12
// baseline (85.670 us; speedup 1.0000x reference)
//
#include <hip/hip_runtime.h>
#include <stdint.h>

// ResidualAttentionBlock: L1-distance attention, 16x511 tokens, 8 heads x 64.
// R12: attn compute loop = R11 (42.7us, best). Changes target the ~40us
//   non-attn remainder: (1) proj re-tiled to 8 tokens/block (1024 blocks,
//   16 waves/CU; was 2 blocks/CU latency-exposed); (2) makek eliminated --
//   attn quantizes K on the fly from x*wk during LDS staging (ds_write
//   direct to swizzled slot; ~1-2 wave-instrs, free) -- drops kq buffer
//   and its HBM round trip.
// Quantization: u = clamp(rint(256*x)+128,0,255); logit = -sad/2048;
// p = 2^(sad * -log2(e)/2048). Validated absmax 0.0156 (thr 0.099).

#define B  16
#define H  8
#define T  511
#define ANUMSZ ((size_t)B * T * H * 64)   // elements per partial-num buffer
#define DENSZ  ((size_t)B * T * H)        // elements per partial-den segment

typedef __fp16 f16x2 __attribute__((ext_vector_type(2)));
typedef __fp16 f16x8 __attribute__((ext_vector_type(8)));
typedef float  f32x4 __attribute__((ext_vector_type(4)));

#if __has_builtin(__builtin_amdgcn_exp2f)
#define EXP2F(x) __builtin_amdgcn_exp2f(x)
#else
#define EXP2F(x) exp2f(x)
#endif

__device__ __forceinline__ uint32_t SAD(uint32_t a, uint32_t b, uint32_t c) {
#if __has_builtin(__builtin_amdgcn_sad_u8)
  return __builtin_amdgcn_sad_u8(a, b, c);
#else
  uint32_t d;
  asm("v_sad_u8 %0, %1, %2, %3" : "=v"(d) : "v"(a), "v"(b), "v"(c));
  return d;
#endif
}

__device__ __forceinline__ uint32_t PKRTZ(float a, float b) {
  f16x2 r = __builtin_amdgcn_cvt_pkrtz(a, b);
  return __builtin_bit_cast(uint32_t, r);
}

__device__ __forceinline__ uint32_t quantu8(float v) {
  float q = __builtin_rintf(__builtin_fmaf(v, 256.f, 128.f));
  q = fminf(fmaxf(q, 0.f), 255.f);
  return (uint32_t)(int)q;
}

// ---------------- weight transpose: wt[k][1024], wft[k][64] ----------------
__global__ void wtrans_kernel(const float* __restrict__ wq, const float* __restrict__ wv,
                              const float* __restrict__ wf, float* __restrict__ wt,
                              float* __restrict__ bias, float* __restrict__ wft,
                              float* __restrict__ biasf) {
  const int idx = blockIdx.x * 256 + (int)threadIdx.x;
  if (idx < 64 * 1024) {
    const int k = idx >> 10, j = idx & 1023;
    const float* src = (j < 512) ? wq : wv;
    const int oc = j & 511;
    wt[idx] = src[oc * 65 + k];
    if (k == 0) bias[j] = src[oc * 65 + 64];
  } else if (idx < 64 * 1024 + 64 * 64) {
    const int r = idx - 64 * 1024;
    const int k = r >> 6, w = r & 63;
    wft[r] = wf[w * 65 + k];
    if (k == 0) biasf[w] = wf[w * 65 + 64];
  }
}

// ------- projection: q->u8 [bh][T][64], v->f16 vt[bh][64][512] -------------
// 8-token tiles, grid (64,B) = 1024 blocks = 4/CU, 16 waves/CU.
__global__ void __launch_bounds__(256, 4) proj_kernel(
    const float* __restrict__ x, const float* __restrict__ wt,
    const float* __restrict__ bias, uint8_t* __restrict__ qq,
    _Float16* __restrict__ vt) {
  __shared__ float xt[64][8];  // [k][tok]
  const int b = blockIdx.y, tc = blockIdx.x;
  const int t0 = tc * 8;
  const int tid = threadIdx.x;
  if (tid < 128) {
    const int tok = tid >> 4, k0 = (tid & 15) * 4;
    const int t = t0 + tok;
    float4 val = {0.f, 0.f, 0.f, 0.f};
    if (t < T) val = *(const float4*)(x + ((size_t)b * T + t) * 64 + k0);
    xt[k0 + 0][tok] = val.x; xt[k0 + 1][tok] = val.y;
    xt[k0 + 2][tok] = val.z; xt[k0 + 3][tok] = val.w;
  }
  __syncthreads();
  const int j0 = tid * 4;
  const float4 bs = *(const float4*)(bias + j0);
  float4 acc[8];
#pragma unroll
  for (int t = 0; t < 8; ++t) acc[t] = bs;
#pragma unroll 8
  for (int k = 0; k < 64; ++k) {
    const float4 w4 = *(const float4*)(wt + (size_t)k * 1024 + j0);
    const float4* xr = (const float4*)xt[k];
    const float4 xa = xr[0], xb = xr[1];
    const float xv[8] = {xa.x, xa.y, xa.z, xa.w, xb.x, xb.y, xb.z, xb.w};
#pragma unroll
    for (int t = 0; t < 8; ++t) {
      acc[t].x = __builtin_fmaf(w4.x, xv[t], acc[t].x);
      acc[t].y = __builtin_fmaf(w4.y, xv[t], acc[t].y);
      acc[t].z = __builtin_fmaf(w4.z, xv[t], acc[t].z);
      acc[t].w = __builtin_fmaf(w4.w, xv[t], acc[t].w);
    }
  }
  const int oc = j0 & 511;
  const int hh = oc >> 6, w0 = oc & 63;
  const size_t bh = (size_t)b * H + hh;
  if (j0 < 512) {  // q side
#pragma unroll
    for (int t = 0; t < 8; ++t) {
      if (t0 + t < T) {
        const uint32_t u = quantu8(acc[t].x) | (quantu8(acc[t].y) << 8) |
                           (quantu8(acc[t].z) << 16) | (quantu8(acc[t].w) << 24);
        *(uint32_t*)(qq + (bh * T + (size_t)(t0 + t)) * 64 + w0) = u;
      }
    }
  } else {  // v side -> transposed vt[bh][w][512]
#pragma unroll
    for (int i = 0; i < 4; ++i) {
      uint32_t u[4];
      const float* a = (const float*)acc;  // acc[t][i] = a[4t+i]
#pragma unroll
      for (int m = 0; m < 4; ++m) u[m] = PKRTZ(a[4 * (2 * m) + i], a[4 * (2 * m + 1) + i]);
      _Float16* p = vt + (bh * 64 + (size_t)(w0 + i)) * 512 + t0;
      *(uint4*)(p) = make_uint4(u[0], u[1], u[2], u[3]);
    }
  }
}

// ---- fused L1 attention: Qw=32, 4-way key-split, on-the-fly K staging -----
// grid (16, H, B): bx = qt(0..3) | kh(0..3)<<2. Block = 4 waves x 32q, keys
// [kh*128, kh*128+128). K computed from x*wk during staging, quantized and
// ds_written directly to the XOR-swizzled slot (chunk j at s*4 + j^((s>>3)&3)).
__global__ void __launch_bounds__(256, 4) attn_kernel(
    const float* __restrict__ x, const float* __restrict__ wk,
    const uint8_t* __restrict__ qq, const _Float16* __restrict__ vt,
    _Float16* __restrict__ anumP, float* __restrict__ denp) {
  __shared__ uint4 klds[512];  // 8 KB: 128-key quarter
  const int bx = blockIdx.x, h = blockIdx.y, b = blockIdx.z;
  const int qt = bx & 3, kh = bx >> 2;
  const int bh = b * H + h;
  const int tid = threadIdx.x;
  const int kbeg = kh * 128;
  {
    // staging: dest chunk d=(s,jd) holds logical chunk jl = jd^((s>>3)&3)
    // of K row kbeg+s, computed as quant(x[row][jl*16..+15] * wk[h][...]).
    const float* xb = x + (size_t)b * T * 64;
    const float* wkh = wk + h * 64;
#pragma unroll
    for (int it = 0; it < 2; ++it) {
      const int d = it * 256 + tid;          // dest chunk index 0..511
      const int s = d >> 2, jd = d & 3;
      const int jl = jd ^ ((s >> 3) & 3);    // logical 16-byte chunk
      const int row = kbeg + s;
      const int rsafe = row < T ? row : T - 1;  // row 511: finite garbage, masked
      const float* xr = xb + (size_t)rsafe * 64 + jl * 16;
      const float* wr = wkh + jl * 16;
      uint32_t u[4];
#pragma unroll
      for (int m = 0; m < 4; ++m) {
        const float4 xv = *(const float4*)(xr + m * 4);
        const float4 wv = *(const float4*)(wr + m * 4);
        u[m] = quantu8(xv.x * wv.x) | (quantu8(xv.y * wv.y) << 8) |
               (quantu8(xv.z * wv.z) << 16) | (quantu8(xv.w * wv.w) << 24);
      }
      klds[d] = make_uint4(u[0], u[1], u[2], u[3]);
    }
  }
  const int wave = tid >> 6, lane = tid & 63;
  const int c = lane & 15, g = lane >> 4;
  const int qb = qt * 128 + wave * 32;
  uint4 q[2][4];
#pragma unroll
  for (int m = 0; m < 2; ++m) {
    const int qm = qb + 16 * m + c;
    const int qsafe = qm < T ? qm : T - 1;
    const uint4* qp = (const uint4*)(qq + ((size_t)bh * T + qsafe) * 64);
#pragma unroll
    for (int i = 0; i < 4; ++i) q[m][i] = qp[i];
  }
  const _Float16* vb = vt + (size_t)bh * 64 * 512;
  f32x4 acc[2][4];
#pragma unroll
  for (int m = 0; m < 2; ++m)
#pragma unroll
    for (int nt = 0; nt < 4; ++nt) acc[m][nt] = f32x4{0.f, 0.f, 0.f, 0.f};
  float den[2] = {0.f, 0.f};
  const float Cl = -0x1.715476p+0f / 2048.0f;  // -log2(e)/2048
  __syncthreads();  // staged K visible

#pragma unroll 1
  for (int kt = 0; kt < 4; ++kt) {
    const int s0 = kbeg + kt * 32;
    // V B-frags (shared by both A-tiles), issued early to hide L2 latency.
    const _Float16* vp0 = vb + (size_t)c * 512 + s0 + g * 8;
    uint4 bvec[4];
#pragma unroll
    for (int nt = 0; nt < 4; ++nt) bvec[nt] = *(const uint4*)(vp0 + nt * 16 * 512);
    uint32_t pk[2][4];  // [tile][jj]
#pragma unroll
    for (int jj = 0; jj < 4; ++jj) {
      float pp[2][2];
#pragma unroll
      for (int e = 0; e < 2; ++e) {
        const int s = s0 + g * 8 + jj * 2 + e;
        const int sl = (s < T ? s : T - 1) - kbeg;  // local staged row
        const uint4* kp = klds + sl * 4;
        const int bb = (sl >> 3) & 3;
        const uint4 k0 = kp[bb], k1 = kp[1 ^ bb], k2 = kp[2 ^ bb], k3 = kp[3 ^ bb];
        const bool live = s < T;
#pragma unroll
        for (int m = 0; m < 2; ++m) {
          uint32_t a0 = 0, a1 = 0;
          a0 = SAD(q[m][0].x, k0.x, a0); a0 = SAD(q[m][0].y, k0.y, a0);
          a0 = SAD(q[m][0].z, k0.z, a0); a0 = SAD(q[m][0].w, k0.w, a0);
          a0 = SAD(q[m][1].x, k1.x, a0); a0 = SAD(q[m][1].y, k1.y, a0);
          a0 = SAD(q[m][1].z, k1.z, a0); a0 = SAD(q[m][1].w, k1.w, a0);
          a1 = SAD(q[m][2].x, k2.x, a1); a1 = SAD(q[m][2].y, k2.y, a1);
          a1 = SAD(q[m][2].z, k2.z, a1); a1 = SAD(q[m][2].w, k2.w, a1);
          a1 = SAD(q[m][3].x, k3.x, a1); a1 = SAD(q[m][3].y, k3.y, a1);
          a1 = SAD(q[m][3].z, k3.z, a1); a1 = SAD(q[m][3].w, k3.w, a1);
          const float p = EXP2F((float)(a0 + a1) * Cl);
          pp[m][e] = live ? p : 0.f;
        }
      }
#pragma unroll
      for (int m = 0; m < 2; ++m) {
        den[m] += pp[m][0] + pp[m][1];
        pk[m][jj] = PKRTZ(pp[m][0], pp[m][1]);
      }
    }
#pragma unroll
    for (int m = 0; m < 2; ++m) {
      const f16x8 af = __builtin_bit_cast(f16x8, make_uint4(pk[m][0], pk[m][1], pk[m][2], pk[m][3]));
#pragma unroll
      for (int nt = 0; nt < 4; ++nt) {
        const f16x8 bf = __builtin_bit_cast(f16x8, bvec[nt]);
        acc[m][nt] = __builtin_amdgcn_mfma_f32_16x16x32_f16(af, bf, acc[m][nt], 0, 0, 0);
      }
    }
  }

  // den: sum the 4 lane-groups (keys split g-wise within the wave).
#pragma unroll
  for (int m = 0; m < 2; ++m) {
    den[m] += __shfl_xor(den[m], 16, 64);
    den[m] += __shfl_xor(den[m], 32, 64);
  }
  // write partial den (one lane-group suffices; den identical across g)
  if (g == 0) {
#pragma unroll
    for (int m = 0; m < 2; ++m) {
      const int qd = qb + 16 * m + c;
      if (qd < T) denp[(size_t)kh * DENSZ + ((size_t)b * T + qd) * H + h] = den[m];
    }
  }
  // write partial num (unnormalized, f16)
  _Float16* abase = anumP + (size_t)kh * ANUMSZ;
#pragma unroll
  for (int m = 0; m < 2; ++m) {
#pragma unroll
    for (int r = 0; r < 4; ++r) {
      const int qr = qb + 16 * m + g * 4 + r;
      if (qr < T) {
        _Float16* ap = abase + (((size_t)b * T + qr) * H + h) * 64 + c;
        ap[0]  = (_Float16)acc[m][0][r];
        ap[16] = (_Float16)acc[m][1][r];
        ap[32] = (_Float16)acc[m][2][r];
        ap[48] = (_Float16)acc[m][3][r];
      }
    }
  }
}

// -------- finalize: combine quarters, softmax-normalize, sum heads, -------
// -------- relu, fanout, residual ------------------------------------------
__global__ void __launch_bounds__(256) finalize_kernel(
    const float* __restrict__ x, const _Float16* __restrict__ anumP,
    const float* __restrict__ denp, const float* __restrict__ wft,
    const float* __restrict__ biasf, float* __restrict__ out) {
  __shared__ float u[4][64];
  __shared__ float rd[4][8];
  const int tid = threadIdx.x;
  const int lt = tid >> 6, w = tid & 63;
  const int gt = blockIdx.x * 4 + lt;  // B*T = 8176 = 2044*4 exactly
  if (w < 8) {
    float d = 1.0f;  // zero-logit sink key
#pragma unroll
    for (int kh = 0; kh < 4; ++kh) d += denp[(size_t)kh * DENSZ + (size_t)gt * H + w];
    rd[lt][w] = 1.0f / d;
  }
  __syncthreads();
  float s = 0.f;
#pragma unroll
  for (int hh = 0; hh < H; ++hh) {
    float n = 0.f;
#pragma unroll
    for (int kh = 0; kh < 4; ++kh)
      n += (float)anumP[(size_t)kh * ANUMSZ + ((size_t)gt * H + hh) * 64 + w];
    s += n * rd[lt][hh];
  }
  u[lt][w] = fmaxf(s, 0.f);
  __syncthreads();
  float y = biasf[w];
#pragma unroll 8
  for (int k = 0; k < 64; ++k) y = __builtin_fmaf(wft[k * 64 + w], u[lt][k], y);
  out[(size_t)gt * 64 + w] = x[(size_t)gt * 64 + w] + y;
}

extern "C" void kernel_launch(void* const* d_in, const int* in_sizes, int n_in,
                              void* d_out, int out_size, void* d_ws, size_t ws_size,
                              hipStream_t stream) {
  (void)in_sizes; (void)n_in; (void)out_size; (void)ws_size;
  const float* x  = (const float*)d_in[0];
  const float* wq = (const float*)d_in[1];
  const float* wv = (const float*)d_in[2];
  const float* wk = (const float*)d_in[3];
  const float* wf = (const float*)d_in[4];
  float* out = (float*)d_out;

  uint8_t* ws = (uint8_t*)d_ws;
  // byte offsets (all 16B-aligned); total ~47.4 MB (ws ~268 MB)
  const size_t o_qq   = 0;                       // B*H*T*64 u8   = 4,186,112
  const size_t o_vt   = 4186112;                 // B*H*64*512 f16= 8,388,608
  const size_t o_anum = 12574720;                // 4x ANUMSZ f16 = 33,488,896
  const size_t o_den  = 46063616;                // 4x DENSZ f32  =  1,046,528
  const size_t o_wt   = 47110144;                // 64*1024 f32   =    262,144
  const size_t o_bias = 47372288;                // 1024 f32
  const size_t o_wft  = 47376384;                // 64*64 f32
  const size_t o_bf   = 47392768;                // 64 f32

  uint8_t*  qq    = ws + o_qq;
  _Float16* vt    = (_Float16*)(ws + o_vt);
  _Float16* anum  = (_Float16*)(ws + o_anum);
  float*    denp  = (float*)(ws + o_den);
  float*    wt    = (float*)(ws + o_wt);
  float*    bias  = (float*)(ws + o_bias);
  float*    wft   = (float*)(ws + o_wft);
  float*    biasf = (float*)(ws + o_bf);

  wtrans_kernel<<<dim3((64 * 1024 + 64 * 64 + 255) / 256), 256, 0, stream>>>(
      wq, wv, wf, wt, bias, wft, biasf);
  proj_kernel<<<dim3(64, B), 256, 0, stream>>>(x, wt, bias, qq, vt);
  attn_kernel<<<dim3(16, H, B), 256, 0, stream>>>(x, wk, qq, vt, anum, denp);
  finalize_kernel<<<dim3(B * T / 4), 256, 0, stream>>>(x, anum, denp, wft, biasf, out);
}

// Round 13
// 84.015 us; speedup vs baseline: 1.0197x; 1.0197x over previous
//
#include <hip/hip_runtime.h>
#include <stdint.h>

// ResidualAttentionBlock: L1-distance attention, 16x511 tokens, 8 heads x 64.
// R13: attn + finalize = R11 byte-exact (attn 42.7us verified best; 4-way
//   key-split partials). Remainder overhauled:
//   - proj rewritten as MFMA f16 GEMM (reuses the attn-verified fragment
//     convention; q-side oriented D[tok][oc] for coalesced qq stores, v-side
//     D[oc][tok] for coalesced vt stores). W stays row-major f16 (no transpose).
//   - prep kernel: x->f16 cast + makek (kq) in one pass.
// Quantization: u = clamp(rint(256*x)+128,0,255); logit = -sad/2048;
// p = 2^(sad * -log2(e)/2048). Validated absmax 0.0156 (thr 0.099).

#define B  16
#define H  8
#define T  511
#define ANUMSZ ((size_t)B * T * H * 64)   // elements per partial-num buffer
#define DENSZ  ((size_t)B * T * H)        // elements per partial-den segment

typedef __fp16 f16x2 __attribute__((ext_vector_type(2)));
typedef __fp16 f16x8 __attribute__((ext_vector_type(8)));
typedef float  f32x4 __attribute__((ext_vector_type(4)));
typedef __attribute__((address_space(3))) uint32_t lds_u32;
typedef __attribute__((address_space(1))) const uint32_t glb_u32;

#if __has_builtin(__builtin_amdgcn_exp2f)
#define EXP2F(x) __builtin_amdgcn_exp2f(x)
#else
#define EXP2F(x) exp2f(x)
#endif

__device__ __forceinline__ uint32_t SAD(uint32_t a, uint32_t b, uint32_t c) {
#if __has_builtin(__builtin_amdgcn_sad_u8)
  return __builtin_amdgcn_sad_u8(a, b, c);
#else
  uint32_t d;
  asm("v_sad_u8 %0, %1, %2, %3" : "=v"(d) : "v"(a), "v"(b), "v"(c));
  return d;
#endif
}

__device__ __forceinline__ uint32_t PKRTZ(float a, float b) {
  f16x2 r = __builtin_amdgcn_cvt_pkrtz(a, b);
  return __builtin_bit_cast(uint32_t, r);
}

__device__ __forceinline__ uint32_t quantu8(float v) {
  float q = __builtin_rintf(__builtin_fmaf(v, 256.f, 128.f));
  q = fminf(fmaxf(q, 0.f), 255.f);
  return (uint32_t)(int)q;
}

// ------- weight prep: Wf16[1024][64] row-major f16, biases, wft ------------
__global__ void wtrans_kernel(const float* __restrict__ wq, const float* __restrict__ wv,
                              const float* __restrict__ wf, _Float16* __restrict__ wf16,
                              float* __restrict__ biasq, float* __restrict__ biasv,
                              float* __restrict__ wft, float* __restrict__ biasf) {
  const int idx = blockIdx.x * 256 + (int)threadIdx.x;
  if (idx < 64 * 1024) {
    const int oc = idx >> 6, k = idx & 63;
    const float* src = (oc < 512) ? wq : wv;
    const int ol = oc & 511;
    wf16[idx] = (_Float16)src[ol * 65 + k];
    if (k == 0) {
      if (oc < 512) biasq[ol] = src[ol * 65 + 64];
      else          biasv[ol] = src[ol * 65 + 64];
    }
  } else if (idx < 64 * 1024 + 64 * 64) {
    const int r = idx - 64 * 1024;
    const int k = r >> 6, w = r & 63;
    wft[r] = wf[w * 65 + k];
    if (k == 0) biasf[w] = wf[w * 65 + 64];
  }
}

// ------- prep: xf16 cast + kq[b][h][t][64] = quant(x*wk[h]) ---------------
__global__ void __launch_bounds__(256) prep_kernel(
    const float* __restrict__ x, const float* __restrict__ wk,
    _Float16* __restrict__ xf16, uint8_t* __restrict__ kq) {
  const int idx = blockIdx.x * 256 + (int)threadIdx.x;
  if (idx >= B * T * 4) return;
  const int row = idx >> 2, part = idx & 3;   // row = b*T + t
  const int b = row / T, t = row - b * T;
  const float* xr = x + (size_t)row * 64 + part * 16;
  float xv[16];
#pragma unroll
  for (int i = 0; i < 4; ++i) {
    const float4 v4 = *(const float4*)(xr + i * 4);
    xv[4 * i] = v4.x; xv[4 * i + 1] = v4.y; xv[4 * i + 2] = v4.z; xv[4 * i + 3] = v4.w;
  }
  {
    uint32_t u[8];
#pragma unroll
    for (int i = 0; i < 8; ++i) u[i] = PKRTZ(xv[2 * i], xv[2 * i + 1]);
    uint32_t* dst = (uint32_t*)(xf16 + (size_t)row * 64 + part * 16);
    *(uint4*)dst       = make_uint4(u[0], u[1], u[2], u[3]);
    *(uint4*)(dst + 4) = make_uint4(u[4], u[5], u[6], u[7]);
  }
#pragma unroll
  for (int h = 0; h < H; ++h) {
    const float* wr = wk + h * 64 + part * 16;
    uint32_t u[4];
#pragma unroll
    for (int i = 0; i < 4; ++i) {
      const float4 wv4 = *(const float4*)(wr + i * 4);
      u[i] = quantu8(xv[4 * i] * wv4.x) | (quantu8(xv[4 * i + 1] * wv4.y) << 8) |
             (quantu8(xv[4 * i + 2] * wv4.z) << 16) | (quantu8(xv[4 * i + 3] * wv4.w) << 24);
    }
    *(uint4*)(kq + (((size_t)b * H + h) * T + t) * 64 + part * 16) = make_uint4(u[0], u[1], u[2], u[3]);
  }
}

// ------- projection via MFMA: q->u8 qq[bh][t][64], v->f16 vt[bh][w][512] ---
// grid (8, 4, B): tg = 64-token group; yy: och = yy>>1 (0:q, 1:v),
// oth = yy&1 (256-oc half). 4 waves x 16 tokens. Fragment convention
// (attn-verified): af reg j = A[c][g*8+j]; bf reg j = B[g*8+j][c];
// D reg r = D[g*4+r][c].
__global__ void __launch_bounds__(256, 2) proj_kernel(
    const _Float16* __restrict__ xf16, const _Float16* __restrict__ wf16,
    const float* __restrict__ biasq, const float* __restrict__ biasv,
    uint8_t* __restrict__ qq, _Float16* __restrict__ vt) {
  const int tg = blockIdx.x, yy = blockIdx.y, b = blockIdx.z;
  const int och = yy >> 1, oth = yy & 1;
  const int tid = threadIdx.x;
  const int wave = tid >> 6, lane = tid & 63;
  const int c = lane & 15, g = lane >> 4;
  const int tokw = tg * 64 + wave * 16;
  const int trow = tokw + c;
  const int tsafe = trow < T ? trow : T - 1;
  const _Float16* xb = xf16 + ((size_t)b * T + tsafe) * 64;
  const f16x8 xf0 = __builtin_bit_cast(f16x8, *(const uint4*)(xb + g * 8));
  const f16x8 xf1 = __builtin_bit_cast(f16x8, *(const uint4*)(xb + 32 + g * 8));

#pragma unroll 4
  for (int ot = 0; ot < 16; ++ot) {
    const int oc0 = och * 512 + oth * 256 + ot * 16;  // global oc tile base
    const _Float16* wb = wf16 + (size_t)(oc0 + c) * 64;
    const f16x8 wf0 = __builtin_bit_cast(f16x8, *(const uint4*)(wb + g * 8));
    const f16x8 wf1 = __builtin_bit_cast(f16x8, *(const uint4*)(wb + 32 + g * 8));
    f32x4 acc = {0.f, 0.f, 0.f, 0.f};
    if (och == 0) {
      // q side: D[tok][oc] -> af = x-frag, bf = W-frag
      acc = __builtin_amdgcn_mfma_f32_16x16x32_f16(xf0, wf0, acc, 0, 0, 0);
      acc = __builtin_amdgcn_mfma_f32_16x16x32_f16(xf1, wf1, acc, 0, 0, 0);
      const int oc = oc0 + c;                 // 0..511
      const int hh = oc >> 6, w0 = oc & 63;
      const float bq = biasq[oc];
      const size_t bhT = ((size_t)b * H + hh) * T;
#pragma unroll
      for (int r = 0; r < 4; ++r) {
        const int t = tokw + g * 4 + r;
        if (t < T) qq[(bhT + t) * 64 + w0] = (uint8_t)quantu8(acc[r] + bq);
      }
    } else {
      // v side: D[oc][tok] -> af = W-frag, bf = x-frag
      acc = __builtin_amdgcn_mfma_f32_16x16x32_f16(wf0, xf0, acc, 0, 0, 0);
      acc = __builtin_amdgcn_mfma_f32_16x16x32_f16(wf1, xf1, acc, 0, 0, 0);
      const int ocv0 = oth * 256 + ot * 16 + g * 4;   // v-local oc 0..511
      const float4 bv = *(const float4*)(biasv + ocv0);
      const float bvr[4] = {bv.x, bv.y, bv.z, bv.w};
      const int t = tokw + c;
      if (t < T) {
#pragma unroll
        for (int r = 0; r < 4; ++r) {
          const int ocv = ocv0 + r;
          const int hh = ocv >> 6, wl = ocv & 63;
          vt[(((size_t)b * H + hh) * 64 + wl) * 512 + t] = (_Float16)(acc[r] + bvr[r]);
        }
      }
    }
  }
}

// ---- fused L1 attention: Qw=32, 4-way key-split blocks, partial output ----
// grid (16, H, B): bx = qt(0..3) | kh(0..3)<<2. Block = 4 waves x 32q, keys
// [kh*128, kh*128+128). 8KB LDS staged via global_load_lds (linear dest,
// source chunk pre-swizzled j^((s>>3)&3); involution => read side unchanged).
__global__ void __launch_bounds__(256, 4) attn_kernel(
    const uint8_t* __restrict__ qq, const uint8_t* __restrict__ kq,
    const _Float16* __restrict__ vt, _Float16* __restrict__ anumP,
    float* __restrict__ denp) {
  __shared__ uint4 klds[512];  // 8 KB: 128-key quarter
  const int bx = blockIdx.x, h = blockIdx.y, b = blockIdx.z;
  const int qt = bx & 3, kh = bx >> 2;
  const int bh = b * H + h;
  const int tid = threadIdx.x;
  const int kbeg = kh * 128;
  {
    // async staging: dest chunk d=(s,j) <- global chunk j^((s>>3)&3)
    // (kh=3: row 127 = key 511 is OOB-garbage, masked in the loop below)
    const uint8_t* kgb = kq + ((size_t)bh * T + kbeg) * 64;
#pragma unroll
    for (int it = 0; it < 2; ++it) {
      const int d = it * 256 + tid;          // dest chunk index 0..511
      const int s = d >> 2, j = d & 3;
      const int sj = j ^ ((s >> 3) & 3);     // swizzled source chunk
      const uint8_t* gsrc = kgb + (size_t)(s * 4 + sj) * 16;
      uint32_t* ldst = (uint32_t*)(klds + it * 256 + (tid >> 6) * 64);  // wave-uniform
      __builtin_amdgcn_global_load_lds((glb_u32*)gsrc, (lds_u32*)ldst, 16, 0, 0);
    }
  }
  const int wave = tid >> 6, lane = tid & 63;
  const int c = lane & 15, g = lane >> 4;
  const int qb = qt * 128 + wave * 32;
  uint4 q[2][4];
#pragma unroll
  for (int m = 0; m < 2; ++m) {
    const int qm = qb + 16 * m + c;
    const int qsafe = qm < T ? qm : T - 1;
    const uint4* qp = (const uint4*)(qq + ((size_t)bh * T + qsafe) * 64);
#pragma unroll
    for (int i = 0; i < 4; ++i) q[m][i] = qp[i];
  }
  const _Float16* vb = vt + (size_t)bh * 64 * 512;
  f32x4 acc[2][4];
#pragma unroll
  for (int m = 0; m < 2; ++m)
#pragma unroll
    for (int nt = 0; nt < 4; ++nt) acc[m][nt] = f32x4{0.f, 0.f, 0.f, 0.f};
  float den[2] = {0.f, 0.f};
  const float Cl = -0x1.715476p+0f / 2048.0f;  // -log2(e)/2048
  __syncthreads();  // drains vmcnt -> staged K visible

#pragma unroll 1
  for (int kt = 0; kt < 4; ++kt) {
    const int s0 = kbeg + kt * 32;
    // V B-frags (shared by both A-tiles), issued early to hide L2 latency.
    const _Float16* vp0 = vb + (size_t)c * 512 + s0 + g * 8;
    uint4 bvec[4];
#pragma unroll
    for (int nt = 0; nt < 4; ++nt) bvec[nt] = *(const uint4*)(vp0 + nt * 16 * 512);
    uint32_t pk[2][4];  // [tile][jj]
#pragma unroll
    for (int jj = 0; jj < 4; ++jj) {
      float pp[2][2];
#pragma unroll
      for (int e = 0; e < 2; ++e) {
        const int s = s0 + g * 8 + jj * 2 + e;
        const int sl = (s < T ? s : T - 1) - kbeg;  // local staged row
        const uint4* kp = klds + sl * 4;
        const int bb = (sl >> 3) & 3;
        const uint4 k0 = kp[bb], k1 = kp[1 ^ bb], k2 = kp[2 ^ bb], k3 = kp[3 ^ bb];
        const bool live = s < T;
#pragma unroll
        for (int m = 0; m < 2; ++m) {
          uint32_t a0 = 0, a1 = 0;
          a0 = SAD(q[m][0].x, k0.x, a0); a0 = SAD(q[m][0].y, k0.y, a0);
          a0 = SAD(q[m][0].z, k0.z, a0); a0 = SAD(q[m][0].w, k0.w, a0);
          a0 = SAD(q[m][1].x, k1.x, a0); a0 = SAD(q[m][1].y, k1.y, a0);
          a0 = SAD(q[m][1].z, k1.z, a0); a0 = SAD(q[m][1].w, k1.w, a0);
          a1 = SAD(q[m][2].x, k2.x, a1); a1 = SAD(q[m][2].y, k2.y, a1);
          a1 = SAD(q[m][2].z, k2.z, a1); a1 = SAD(q[m][2].w, k2.w, a1);
          a1 = SAD(q[m][3].x, k3.x, a1); a1 = SAD(q[m][3].y, k3.y, a1);
          a1 = SAD(q[m][3].z, k3.z, a1); a1 = SAD(q[m][3].w, k3.w, a1);
          const float p = EXP2F((float)(a0 + a1) * Cl);
          pp[m][e] = live ? p : 0.f;
        }
      }
#pragma unroll
      for (int m = 0; m < 2; ++m) {
        den[m] += pp[m][0] + pp[m][1];
        pk[m][jj] = PKRTZ(pp[m][0], pp[m][1]);
      }
    }
#pragma unroll
    for (int m = 0; m < 2; ++m) {
      const f16x8 af = __builtin_bit_cast(f16x8, make_uint4(pk[m][0], pk[m][1], pk[m][2], pk[m][3]));
#pragma unroll
      for (int nt = 0; nt < 4; ++nt) {
        const f16x8 bf = __builtin_bit_cast(f16x8, bvec[nt]);
        acc[m][nt] = __builtin_amdgcn_mfma_f32_16x16x32_f16(af, bf, acc[m][nt], 0, 0, 0);
      }
    }
  }

  // den: sum the 4 lane-groups (keys split g-wise within the wave).
#pragma unroll
  for (int m = 0; m < 2; ++m) {
    den[m] += __shfl_xor(den[m], 16, 64);
    den[m] += __shfl_xor(den[m], 32, 64);
  }
  // write partial den (one lane-group suffices; den identical across g)
  if (g == 0) {
#pragma unroll
    for (int m = 0; m < 2; ++m) {
      const int qd = qb + 16 * m + c;
      if (qd < T) denp[(size_t)kh * DENSZ + ((size_t)b * T + qd) * H + h] = den[m];
    }
  }
  // write partial num (unnormalized, f16)
  _Float16* abase = anumP + (size_t)kh * ANUMSZ;
#pragma unroll
  for (int m = 0; m < 2; ++m) {
#pragma unroll
    for (int r = 0; r < 4; ++r) {
      const int qr = qb + 16 * m + g * 4 + r;
      if (qr < T) {
        _Float16* ap = abase + (((size_t)b * T + qr) * H + h) * 64 + c;
        ap[0]  = (_Float16)acc[m][0][r];
        ap[16] = (_Float16)acc[m][1][r];
        ap[32] = (_Float16)acc[m][2][r];
        ap[48] = (_Float16)acc[m][3][r];
      }
    }
  }
}

// -------- finalize: combine quarters, softmax-normalize, sum heads, -------
// -------- relu, fanout, residual ------------------------------------------
__global__ void __launch_bounds__(256) finalize_kernel(
    const float* __restrict__ x, const _Float16* __restrict__ anumP,
    const float* __restrict__ denp, const float* __restrict__ wft,
    const float* __restrict__ biasf, float* __restrict__ out) {
  __shared__ float u[4][64];
  __shared__ float rd[4][8];
  const int tid = threadIdx.x;
  const int lt = tid >> 6, w = tid & 63;
  const int gt = blockIdx.x * 4 + lt;  // B*T = 8176 = 2044*4 exactly
  if (w < 8) {
    float d = 1.0f;  // zero-logit sink key
#pragma unroll
    for (int kh = 0; kh < 4; ++kh) d += denp[(size_t)kh * DENSZ + (size_t)gt * H + w];
    rd[lt][w] = 1.0f / d;
  }
  __syncthreads();
  float s = 0.f;
#pragma unroll
  for (int hh = 0; hh < H; ++hh) {
    float n = 0.f;
#pragma unroll
    for (int kh = 0; kh < 4; ++kh)
      n += (float)anumP[(size_t)kh * ANUMSZ + ((size_t)gt * H + hh) * 64 + w];
    s += n * rd[lt][hh];
  }
  u[lt][w] = fmaxf(s, 0.f);
  __syncthreads();
  float y = biasf[w];
#pragma unroll 8
  for (int k = 0; k < 64; ++k) y = __builtin_fmaf(wft[k * 64 + w], u[lt][k], y);
  out[(size_t)gt * 64 + w] = x[(size_t)gt * 64 + w] + y;
}

extern "C" void kernel_launch(void* const* d_in, const int* in_sizes, int n_in,
                              void* d_out, int out_size, void* d_ws, size_t ws_size,
                              hipStream_t stream) {
  (void)in_sizes; (void)n_in; (void)out_size; (void)ws_size;
  const float* x  = (const float*)d_in[0];
  const float* wq = (const float*)d_in[1];
  const float* wv = (const float*)d_in[2];
  const float* wk = (const float*)d_in[3];
  const float* wf = (const float*)d_in[4];
  float* out = (float*)d_out;

  uint8_t* ws = (uint8_t*)d_ws;
  // byte offsets (all 16B-aligned); total ~52.5 MB (ws ~268 MB)
  const size_t o_qq   = 0;                       // B*H*T*64 u8   = 4,186,112
  const size_t o_kq   = 4186112;                 // B*H*T*64 u8   = 4,186,112
  const size_t o_vt   = 8372224;                 // B*H*64*512 f16= 8,388,608
  const size_t o_anum = 16760832;                // 4x ANUMSZ f16 = 33,488,896
  const size_t o_den  = 50249728;                // 4x DENSZ f32  =  1,046,528
  const size_t o_wf16 = 51296256;                // 1024*64 f16   =    131,072
  const size_t o_xf16 = 51427328;                // B*T*64 f16    =  1,046,528
  const size_t o_bq   = 52473856;                // 512 f32
  const size_t o_bv   = 52475904;                // 512 f32
  const size_t o_wft  = 52477952;                // 64*64 f32
  const size_t o_bf   = 52494336;                // 64 f32

  uint8_t*  qq    = ws + o_qq;
  uint8_t*  kq    = ws + o_kq;
  _Float16* vt    = (_Float16*)(ws + o_vt);
  _Float16* anum  = (_Float16*)(ws + o_anum);
  float*    denp  = (float*)(ws + o_den);
  _Float16* wf16  = (_Float16*)(ws + o_wf16);
  _Float16* xf16  = (_Float16*)(ws + o_xf16);
  float*    biasq = (float*)(ws + o_bq);
  float*    biasv = (float*)(ws + o_bv);
  float*    wft   = (float*)(ws + o_wft);
  float*    biasf = (float*)(ws + o_bf);

  wtrans_kernel<<<dim3((64 * 1024 + 64 * 64 + 255) / 256), 256, 0, stream>>>(
      wq, wv, wf, wf16, biasq, biasv, wft, biasf);
  prep_kernel<<<dim3((B * T * 4 + 255) / 256), 256, 0, stream>>>(x, wk, xf16, kq);
  proj_kernel<<<dim3(8, 4, B), 256, 0, stream>>>(xf16, wf16, biasq, biasv, qq, vt);
  attn_kernel<<<dim3(16, H, B), 256, 0, stream>>>(qq, kq, vt, anum, denp);
  finalize_kernel<<<dim3(B * T / 4), 256, 0, stream>>>(x, anum, denp, wft, biasf, out);
}